// Round 2
// baseline (4112.111 us; speedup 1.0000x reference)
//
#include <hip/hip_runtime.h>
#include <hip/hip_bf16.h>
#include <hip/hip_fp16.h>

#define DI     2048
#define LSEQ   2048
#define NBATCH 2
#define MROWS  4096        // NBATCH * LSEQ
#define EPSF   1e-5f
#define NSTEPS 31
#define NCH    32          // scan chunks
#define CL     64          // chunk length (NCH*CL == LSEQ)

typedef float    f32x4 __attribute__((ext_vector_type(4)));
typedef _Float16 f16x8 __attribute__((ext_vector_type(8)));
using f16 = _Float16;

// ------------------------- static device arena -------------------------
constexpr size_t OFF_APARAM = 0;                                   // f16 [4096][4096]  = [x_i | h_sh]
constexpr size_t OFF_WVT    = OFF_APARAM + (size_t)4096*4096*2;    // f16 [2048][4096]  W_v^T
constexpr size_t OFF_WCT    = OFF_WVT    + (size_t)2048*4096*2;    // f16 [2048][4096]  W_c^T
constexpr size_t OFF_WBT    = OFF_WCT    + (size_t)2048*4096*2;    // f16 [2048][2048]  W_b^T
constexpr size_t OFF_WLT    = OFF_WBT    + (size_t)2048*2048*2;    // f16 [2048][2048]  W_lam^T
constexpr size_t OFF_WINT   = OFF_WLT    + (size_t)2048*2048*2;    // f16 [4096][1024]  W_in^T
constexpr size_t OFF_WOT    = OFF_WINT   + (size_t)4096*1024*2;    // f16 [1024][2048]  W_out^T
constexpr size_t OFF_AX     = OFF_WOT    + (size_t)1024*2048*2;    // f16 [4096][1024]  x
constexpr size_t OFF_Z      = OFF_AX     + (size_t)4096*1024*2;    // f16 [4096][2048]  z
constexpr size_t OFF_U      = OFF_Z      + (size_t)4096*2048*2;    // f16 [4096][2048]  u (normed)
constexpr size_t OFF_XI     = OFF_U      + (size_t)4096*2048*2;    // f32  [4096][2048]  x_i
constexpr size_t OFF_BX     = OFF_XI     + (size_t)4096*2048*4;    // f32  b*x_i
constexpr size_t OFF_LAM    = OFF_BX     + (size_t)4096*2048*4;    // f32  lam
constexpr size_t OFF_H      = OFF_LAM    + (size_t)4096*2048*4;    // f32  h
constexpr size_t OFF_INP    = OFF_H      + (size_t)4096*2048*4;    // f32  scan input
constexpr size_t OFF_GOUT   = OFF_INP    + (size_t)4096*2048*4;    // f32  v_raw / u_raw
constexpr size_t OFF_VX     = OFF_GOUT   + (size_t)4096*2048*4;    // f32  x_i @ W_v_top
constexpr size_t OFF_CA     = OFF_VX     + (size_t)4096*2048*4;    // f32  [2*32][2048] chunk A
constexpr size_t OFF_CB     = OFF_CA     + (size_t)NBATCH*NCH*2048*4;
constexpr size_t ARENA_SZ   = OFF_CB     + (size_t)NBATCH*NCH*2048*4;

__device__ __align__(256) char g_buf[ARENA_SZ];

// ------------------------- helpers -------------------------
__device__ __forceinline__ void gload16(const void* g, void* l) {
  __builtin_amdgcn_global_load_lds((const __attribute__((address_space(1))) void*)g,
                                   (__attribute__((address_space(3))) void*)l, 16, 0, 0);
}
__device__ __forceinline__ float siluf(float x) { return x / (1.0f + __expf(-x)); }
__device__ __forceinline__ float sigmf(float x) { return 1.0f / (1.0f + __expf(-x)); }

// ------------------------- GEMM: C = A(f16,MxK) * Bt(f16,NxK)^T, templated epilogue ----
// EPI 0: outf[row*N+col] = acc                              (vx precompute, final out)
// EPI 1: split xz: col<DI -> xi(f32)+Aparam(f16) ; else z(f16)
// EPI 2: bx = silu(acc) * xi
// EPI 3: lam = sigmoid(acc + bias[col])
// EPI 4: v_raw = silu(acc + vx[idx] + bias[col])
// EPI 5: u_raw = silu(acc) * h[idx] * silu(z[idx])
template<int EPI>
__global__ __launch_bounds__(256) void gemm_f16(
    const f16* __restrict__ A, int lda,
    const f16* __restrict__ Bt, int ldb,
    int N, int K,
    float* __restrict__ outf,
    f16* __restrict__ outb,
    f16* __restrict__ outb2,
    const float* __restrict__ aux0,
    const float* __restrict__ aux1,
    const f16* __restrict__ auxb)
{
  __shared__ char As[128 * 128];   // 128 rows x 64 f16 (128B per row)
  __shared__ char Bs[128 * 128];

  const int tid = threadIdx.x;
  const int l   = tid & 63;
  const int w   = tid >> 6;
  const int wm  = (w >> 1) << 6;   // wave sub-tile origin (2x2 waves of 64x64)
  const int wn  = (w & 1) << 6;
  const int ntn = N >> 7;
  const int bm  = blockIdx.x / ntn;
  const int bn  = blockIdx.x % ntn;
  const size_t m0 = (size_t)bm << 7;
  const size_t n0 = (size_t)bn << 7;

  const char* Ab = (const char*)A + m0 * (size_t)(lda * 2);
  const char* Bb = (const char*)Bt + n0 * (size_t)(ldb * 2);

  f32x4 acc[4][4];
#pragma unroll
  for (int i = 0; i < 4; ++i)
#pragma unroll
    for (int j = 0; j < 4; ++j) acc[i][j] = (f32x4){0.f, 0.f, 0.f, 0.f};

  for (int kt = 0; kt < K; kt += 64) {
    // stage 128x64 A-tile and B-tile; linear LDS dest, XOR-swizzled global source col
#pragma unroll
    for (int rep = 0; rep < 4; ++rep) {
      const int o   = tid + (rep << 8);      // 16B-chunk index, 0..1023
      const int r   = o >> 3;                // tile row 0..127
      const int cb  = (o & 7) << 4;          // byte col within 128B row
      const int scb = cb ^ ((r & 7) << 4);   // pre-swizzled source col
      gload16(Ab + (size_t)r * (size_t)(lda * 2) + (size_t)kt * 2 + scb, As + (o << 4));
      gload16(Bb + (size_t)r * (size_t)(ldb * 2) + (size_t)kt * 2 + scb, Bs + (o << 4));
    }
    __syncthreads();   // drains vmcnt before barrier
#pragma unroll
    for (int kk = 0; kk < 2; ++kk) {
      f16x8 af[4], bfr[4];
      const int kb = (kk << 6) + ((l >> 4) << 4);   // byte offset of this lane's k-slice
#pragma unroll
      for (int i = 0; i < 4; ++i) {
        const int Ra = wm + (i << 4) + (l & 15);
        af[i]  = *(const f16x8*)(As + (Ra << 7) + (kb ^ ((Ra & 7) << 4)));
        const int Rb = wn + (i << 4) + (l & 15);
        bfr[i] = *(const f16x8*)(Bs + (Rb << 7) + (kb ^ ((Rb & 7) << 4)));
      }
#pragma unroll
      for (int i = 0; i < 4; ++i)
#pragma unroll
        for (int j = 0; j < 4; ++j)
          acc[i][j] = __builtin_amdgcn_mfma_f32_16x16x32_f16(af[i], bfr[j], acc[i][j], 0, 0, 0);
    }
    __syncthreads();
  }

  // epilogue: C/D layout col=lane&15, row=(lane>>4)*4+reg  [m89-verified, dtype-independent]
#pragma unroll
  for (int i = 0; i < 4; ++i) {
#pragma unroll
    for (int j = 0; j < 4; ++j) {
#pragma unroll
      for (int rg = 0; rg < 4; ++rg) {
        const size_t row = m0 + wm + (i << 4) + ((l >> 4) << 2) + rg;
        const size_t col = n0 + wn + (j << 4) + (l & 15);
        const float v = acc[i][j][rg];
        if constexpr (EPI == 0) {
          outf[row * (size_t)N + col] = v;
        } else if constexpr (EPI == 1) {
          if (col < DI) {
            outf[(row << 11) + col] = v;
            outb[(row << 12) + col] = (f16)v;
          } else {
            outb2[(row << 11) + (col - DI)] = (f16)v;
          }
        } else if constexpr (EPI == 2) {
          const size_t idx = (row << 11) + col;
          outf[idx] = siluf(v) * aux0[idx];
        } else if constexpr (EPI == 3) {
          outf[(row << 11) + col] = sigmf(v + aux1[col]);
        } else if constexpr (EPI == 4) {
          const size_t idx = (row << 11) + col;
          outf[idx] = siluf(v + aux0[idx] + aux1[col]);
        } else if constexpr (EPI == 5) {
          const size_t idx = (row << 11) + col;
          const float zz = (float)auxb[idx];
          outf[idx] = siluf(v) * aux0[idx] * siluf(zz);
        }
      }
    }
  }
}

// ------------------------- prep kernels -------------------------
__global__ __launch_bounds__(256) void transpose_f32_f16(
    const float* __restrict__ in, f16* __restrict__ out, int R, int C)
{
  __shared__ float t[32][33];
  const int bx = blockIdx.x * 32;  // input col
  const int by = blockIdx.y * 32;  // input row
  const int lx = threadIdx.x;      // 0..31
  const int ly = threadIdx.y;      // 0..7
#pragma unroll
  for (int i = 0; i < 32; i += 8)
    t[ly + i][lx] = in[(size_t)(by + ly + i) * C + bx + lx];
  __syncthreads();
#pragma unroll
  for (int i = 0; i < 32; i += 8)
    out[(size_t)(bx + ly + i) * R + by + lx] = (f16)t[lx][ly + i];
}

__global__ __launch_bounds__(256) void cast_f32_f16(
    const float* __restrict__ in, f16* __restrict__ out, int n)
{
  const int i = blockIdx.x * 256 + threadIdx.x;
  if (i < n) out[i] = (f16)in[i];
}

__global__ __launch_bounds__(256) void fill_init(
    float* __restrict__ h, f16* __restrict__ Aparam)
{
  const int idx = blockIdx.x * 256 + threadIdx.x;   // 0 .. 4096*2048-1
  h[idx] = 0.0f;
  const int r = idx >> 11, c = idx & 2047;
  Aparam[((size_t)r << 12) + DI + c] = (f16)0.0f;
}

// ------------------------- per-step elementwise (Householder) -------------------------
// x_tilde = bx - 2*dot(dx, v_n)*v_n  with v_n = v_raw/(||v_raw||+eps), dx = bx - h
// inp = (1-lam) * x_tilde
__global__ __launch_bounds__(256) void elemwise_step(
    const float* __restrict__ vraw, const float* __restrict__ bx,
    const float* __restrict__ h, const float* __restrict__ lam,
    float* __restrict__ inp)
{
  const int row = blockIdx.x;
  const size_t base = (size_t)row << 11;
  const int tid = threadIdx.x;
  float v[8], bxv[8];
  float ss = 0.f, dr = 0.f;
#pragma unroll
  for (int k = 0; k < 8; ++k) {
    const int c = tid + (k << 8);
    const float vv = vraw[base + c];
    const float bb = bx[base + c];
    const float dx = bb - h[base + c];
    v[k] = vv; bxv[k] = bb;
    ss += vv * vv;
    dr += dx * vv;
  }
#pragma unroll
  for (int off = 32; off; off >>= 1) {
    ss += __shfl_xor(ss, off);
    dr += __shfl_xor(dr, off);
  }
  __shared__ float sred[8];
  const int l = tid & 63, w = tid >> 6;
  if (l == 0) { sred[w] = ss; sred[4 + w] = dr; }
  __syncthreads();
  ss = sred[0] + sred[1] + sred[2] + sred[3];
  dr = sred[4] + sred[5] + sred[6] + sred[7];
  const float inv = 1.0f / (sqrtf(ss) + EPSF);
  const float sc = 2.0f * dr * inv * inv;
#pragma unroll
  for (int k = 0; k < 8; ++k) {
    const int c = tid + (k << 8);
    inp[base + c] = (1.0f - lam[base + c]) * (bxv[k] - sc * v[k]);
  }
}

// ------------------------- chunked linear recurrence h[t] = lam[t]*h[t-1] + inp[t] ------
__global__ __launch_bounds__(256) void scan_pass1(
    const float* __restrict__ lam, const float* __restrict__ inp,
    float* __restrict__ cA, float* __restrict__ cB)
{
  const int bid = blockIdx.x;
  const int dg = bid & 7, ch = (bid >> 3) & (NCH - 1), b = bid >> 8;
  const int d = (dg << 8) + threadIdx.x;
  const size_t base = ((size_t)b * LSEQ) * DI + d;
  const int t0 = ch * CL;
  float A = 1.f, Bv = 0.f;
  for (int t = t0; t < t0 + CL; ++t) {
    const float la = lam[base + (size_t)t * DI];
    const float x  = inp[base + (size_t)t * DI];
    Bv = la * Bv + x;
    A *= la;
  }
  const size_t ci = ((size_t)(b * NCH + ch)) * DI + d;
  cA[ci] = A; cB[ci] = Bv;
}

__global__ __launch_bounds__(256) void scan_pass2(
    const float* __restrict__ lam, const float* __restrict__ inp,
    const float* __restrict__ cA, const float* __restrict__ cB,
    float* __restrict__ h, f16* __restrict__ Aparam)
{
  const int bid = blockIdx.x;
  const int dg = bid & 7, ch = (bid >> 3) & (NCH - 1), b = bid >> 8;
  const int d = (dg << 8) + threadIdx.x;
  const size_t base = ((size_t)b * LSEQ) * DI + d;
  const int t0 = ch * CL;
  float hv = 0.f;
  for (int cc = 0; cc < ch; ++cc) {       // combine preceding chunk summaries
    const size_t ci = ((size_t)(b * NCH + cc)) * DI + d;
    hv = cA[ci] * hv + cB[ci];
  }
  for (int t = t0; t < t0 + CL; ++t) {
    const size_t idx = base + (size_t)t * DI;
    hv = lam[idx] * hv + inp[idx];
    h[idx] = hv;
    if (t < LSEQ - 1)   // shifted h -> A matrix second half (next step's GEMM operand)
      Aparam[((size_t)(b * LSEQ + t + 1) << 12) + DI + d] = (f16)hv;
  }
}

// ------------------------- final RMS norm -------------------------
__global__ __launch_bounds__(256) void rms_norm(
    const float* __restrict__ uraw, const float* __restrict__ gn,
    f16* __restrict__ u)
{
  const int row = blockIdx.x;
  const size_t base = (size_t)row << 11;
  const int tid = threadIdx.x;
  float uv[8];
  float ss = 0.f;
#pragma unroll
  for (int k = 0; k < 8; ++k) {
    const int c = tid + (k << 8);
    uv[k] = uraw[base + c];
    ss += uv[k] * uv[k];
  }
#pragma unroll
  for (int off = 32; off; off >>= 1) ss += __shfl_xor(ss, off);
  __shared__ float sred[4];
  const int l = tid & 63, w = tid >> 6;
  if (l == 0) sred[w] = ss;
  __syncthreads();
  ss = sred[0] + sred[1] + sred[2] + sred[3];
  const float scale = 1.0f / sqrtf(ss * (1.0f / DI) + EPSF);
#pragma unroll
  for (int k = 0; k < 8; ++k) {
    const int c = tid + (k << 8);
    u[base + c] = (f16)(uv[k] * scale * gn[c]);
  }
}

// ------------------------- launch -------------------------
extern "C" void kernel_launch(void* const* d_in, const int* in_sizes, int n_in,
                              void* d_out, int out_size, void* d_ws, size_t ws_size,
                              hipStream_t stream)
{
  (void)in_sizes; (void)n_in; (void)out_size; (void)d_ws; (void)ws_size;
  const float* x      = (const float*)d_in[0];
  const float* W_in   = (const float*)d_in[1];
  const float* W_b    = (const float*)d_in[2];
  const float* W_lam  = (const float*)d_in[3];
  const float* b_lam  = (const float*)d_in[4];
  const float* W_v    = (const float*)d_in[5];
  const float* b_v    = (const float*)d_in[6];
  const float* W_c    = (const float*)d_in[7];
  const float* g_norm = (const float*)d_in[8];
  const float* W_out  = (const float*)d_in[9];
  float* out = (float*)d_out;

  char* buf = nullptr;
  hipGetSymbolAddress((void**)&buf, HIP_SYMBOL(g_buf));

  f16* Aparam = (f16*)(buf + OFF_APARAM);
  f16* Wvt    = (f16*)(buf + OFF_WVT);
  f16* Wct    = (f16*)(buf + OFF_WCT);
  f16* Wbt    = (f16*)(buf + OFF_WBT);
  f16* Wlt    = (f16*)(buf + OFF_WLT);
  f16* Wint   = (f16*)(buf + OFF_WINT);
  f16* Wot    = (f16*)(buf + OFF_WOT);
  f16* Ax     = (f16*)(buf + OFF_AX);
  f16* Zb     = (f16*)(buf + OFF_Z);
  f16* Ub     = (f16*)(buf + OFF_U);
  float* xi   = (float*)(buf + OFF_XI);
  float* bx   = (float*)(buf + OFF_BX);
  float* lam  = (float*)(buf + OFF_LAM);
  float* h    = (float*)(buf + OFF_H);
  float* inp  = (float*)(buf + OFF_INP);
  float* gout = (float*)(buf + OFF_GOUT);
  float* vx   = (float*)(buf + OFF_VX);
  float* cA   = (float*)(buf + OFF_CA);
  float* cB   = (float*)(buf + OFF_CB);

  const dim3 b256(256);
  const dim3 tb(32, 8);

  // init h = 0, Aparam h-half = 0
  fill_init<<<dim3(MROWS * DI / 256), b256, 0, stream>>>(h, Aparam);

  // weight transposes (f32 -> f16, K-major)
  transpose_f32_f16<<<dim3(4096 / 32, 1024 / 32), tb, 0, stream>>>(W_in,  Wint, 1024, 4096);
  transpose_f32_f16<<<dim3(2048 / 32, 2048 / 32), tb, 0, stream>>>(W_b,   Wbt,  2048, 2048);
  transpose_f32_f16<<<dim3(2048 / 32, 2048 / 32), tb, 0, stream>>>(W_lam, Wlt,  2048, 2048);
  transpose_f32_f16<<<dim3(2048 / 32, 4096 / 32), tb, 0, stream>>>(W_v,   Wvt,  4096, 2048);
  transpose_f32_f16<<<dim3(2048 / 32, 4096 / 32), tb, 0, stream>>>(W_c,   Wct,  4096, 2048);
  transpose_f32_f16<<<dim3(1024 / 32, 2048 / 32), tb, 0, stream>>>(W_out, Wot,  2048, 1024);
  cast_f32_f16<<<dim3(MROWS * 1024 / 256), b256, 0, stream>>>(x, Ax, MROWS * 1024);

  // xz = x @ W_in  -> xi (f32 + f16 into Aparam), z (f16)
  gemm_f16<1><<<dim3(32 * 32), b256, 0, stream>>>(Ax, 1024, Wint, 1024, 4096, 1024,
                                                  xi, Aparam, Zb, nullptr, nullptr, nullptr);
  // bx = silu(x_i @ W_b) * x_i
  gemm_f16<2><<<dim3(32 * 16), b256, 0, stream>>>(Aparam, 4096, Wbt, 2048, 2048, 2048,
                                                  bx, nullptr, nullptr, xi, nullptr, nullptr);
  // lam = sigmoid(x_i @ W_lam + b_lam)
  gemm_f16<3><<<dim3(32 * 16), b256, 0, stream>>>(Aparam, 4096, Wlt, 2048, 2048, 2048,
                                                  lam, nullptr, nullptr, nullptr, b_lam, nullptr);
  // vx = x_i @ W_v[:DI]   (loop-invariant half of the param GEMM)
  gemm_f16<0><<<dim3(32 * 16), b256, 0, stream>>>(Aparam, 4096, Wvt, 4096, 2048, 2048,
                                                  vx, nullptr, nullptr, nullptr, nullptr, nullptr);

  for (int s = 0; s < NSTEPS; ++s) {
    // v_raw = silu(h_sh @ W_v[DI:] + vx + b_v)
    gemm_f16<4><<<dim3(32 * 16), b256, 0, stream>>>(Aparam + DI, 4096, Wvt + DI, 4096, 2048, 2048,
                                                    gout, nullptr, nullptr, vx, b_v, nullptr);
    elemwise_step<<<dim3(MROWS), b256, 0, stream>>>(gout, bx, h, lam, inp);
    scan_pass1<<<dim3(NBATCH * NCH * 8), b256, 0, stream>>>(lam, inp, cA, cB);
    scan_pass2<<<dim3(NBATCH * NCH * 8), b256, 0, stream>>>(lam, inp, cA, cB, h, Aparam);
  }

  // u_raw = silu([x_i|h_sh] @ W_c) * h * silu(z)
  gemm_f16<5><<<dim3(32 * 16), b256, 0, stream>>>(Aparam, 4096, Wct, 4096, 2048, 4096,
                                                  gout, nullptr, nullptr, h, nullptr, Zb);
  rms_norm<<<dim3(MROWS), b256, 0, stream>>>(gout, g_norm, Ub);
  // out = u @ W_out
  gemm_f16<0><<<dim3(32 * 8), b256, 0, stream>>>(Ub, 2048, Wot, 2048, 1024, 2048,
                                                 out, nullptr, nullptr, nullptr, nullptr, nullptr);
}